// Round 1
// baseline (173.723 us; speedup 1.0000x reference)
//
#include <hip/hip_runtime.h>

typedef unsigned short u16;
typedef unsigned short u16x8 __attribute__((ext_vector_type(8)));
typedef __bf16 bf16x8 __attribute__((ext_vector_type(8)));
typedef float f32x4 __attribute__((ext_vector_type(4)));

// Problem constants
#define NN 4096     // nodes
#define KD 512      // IN_DIM (= GEMM K)
#define HD 512      // OUT_DIM*NUM_HEADS
#define NT 1536     // fused QKV output cols

__device__ __forceinline__ u16 f2bf(float f) {
    unsigned u = __builtin_bit_cast(unsigned, f);
    u += 0x7fffu + ((u >> 16) & 1u);
    return (u16)(u >> 16);
}
__device__ __forceinline__ float bf2f(u16 u) {
    return __builtin_bit_cast(float, ((unsigned)u) << 16);
}

// ---- h (fp32) -> bf16 ----
__global__ void k_cvt_h(const float4* __restrict__ in, u16* __restrict__ out) {
    int i = blockIdx.x * blockDim.x + threadIdx.x;   // over 524288 float4s
    float4 f = in[i];
    ((ushort4*)out)[i] = make_ushort4(f2bf(f.x), f2bf(f.y), f2bf(f.z), f2bf(f.w));
}

// ---- fused W^T (1536 x 512) bf16; q-part pre-scaled by 1/8 ----
__global__ void k_w(const float* __restrict__ Wq, const float* __restrict__ Wk,
                    const float* __restrict__ Wv, u16* __restrict__ wt) {
    __shared__ float tile[32][33];
    int z = blockIdx.z;
    const float* W = (z == 0) ? Wq : ((z == 1) ? Wk : Wv);
    float scale = (z == 0) ? 0.125f : 1.0f;
    int j0 = blockIdx.x * 32;   // output col of W (head*dim index)
    int k0 = blockIdx.y * 32;   // input dim
    int tx = threadIdx.x, ty = threadIdx.y;   // 32 x 8
    #pragma unroll
    for (int r = 0; r < 32; r += 8)
        tile[ty + r][tx] = W[(size_t)(k0 + ty + r) * HD + j0 + tx];
    __syncthreads();
    #pragma unroll
    for (int r = 0; r < 32; r += 8)
        wt[(size_t)(z * 512 + j0 + ty + r) * KD + k0 + tx] = f2bf(scale * tile[tx][ty + r]);
}

// ---- fused bias (q-part pre-scaled) ----
__global__ void k_bias(const float* __restrict__ bq, const float* __restrict__ bk,
                       const float* __restrict__ bv, float* __restrict__ biasf) {
    int t = threadIdx.x, b = blockIdx.x;
    float v = (b == 0) ? bq[t] * 0.125f : ((b == 1) ? bk[t] : bv[t]);
    biasf[b * 512 + t] = v;
}

// ---- QKV GEMM: (4096x512) x (512x1536) + bias.  128x128 tile, BK=32, 4 waves ----
__global__ __launch_bounds__(256) void k_gemm(const u16* __restrict__ hb,
        const u16* __restrict__ wt, const float* __restrict__ biasf,
        float* __restrict__ qbuf, u16* __restrict__ kbuf, u16* __restrict__ vbuf)
{
    __shared__ u16 As[128 * 32];
    __shared__ u16 Bs[128 * 32];
    const int tid = threadIdx.x;
    const int w = tid >> 6, lane = tid & 63;
    const int wr = w >> 1, wc = w & 1;
    const int l16 = lane & 15, half = lane >> 4;
    const int row0 = blockIdx.x * 128, col0 = blockIdx.y * 128;

    const int crow = tid >> 2, c8 = (tid & 3) * 8;
    const u16* gA0 = hb + (size_t)(row0 + crow) * KD + c8;
    const u16* gA1 = gA0 + (size_t)64 * KD;
    const u16* gB0 = wt + (size_t)(col0 + crow) * KD + c8;
    const u16* gB1 = gB0 + (size_t)64 * KD;

    f32x4 acc[4][4] = {};

    for (int kk = 0; kk < KD; kk += 32) {
        u16x8 a0 = *(const u16x8*)(gA0 + kk);
        u16x8 a1 = *(const u16x8*)(gA1 + kk);
        u16x8 b0 = *(const u16x8*)(gB0 + kk);
        u16x8 b1 = *(const u16x8*)(gB1 + kk);
        __syncthreads();
        *(u16x8*)&As[tid * 8] = a0;
        *(u16x8*)&As[(tid + 256) * 8] = a1;
        *(u16x8*)&Bs[tid * 8] = b0;
        *(u16x8*)&Bs[(tid + 256) * 8] = b1;
        __syncthreads();
        bf16x8 af[4], bfr[4];
        #pragma unroll
        for (int mi = 0; mi < 4; ++mi)
            af[mi] = *(const bf16x8*)&As[(wr * 64 + mi * 16 + l16) * 32 + half * 8];
        #pragma unroll
        for (int ni = 0; ni < 4; ++ni)
            bfr[ni] = *(const bf16x8*)&Bs[(wc * 64 + ni * 16 + l16) * 32 + half * 8];
        #pragma unroll
        for (int mi = 0; mi < 4; ++mi)
            #pragma unroll
            for (int ni = 0; ni < 4; ++ni)
                acc[mi][ni] = __builtin_amdgcn_mfma_f32_16x16x32_bf16(
                    af[mi], bfr[ni], acc[mi][ni], 0, 0, 0);
    }

    #pragma unroll
    for (int mi = 0; mi < 4; ++mi) {
        #pragma unroll
        for (int ni = 0; ni < 4; ++ni) {
            int j = col0 + wc * 64 + ni * 16 + l16;
            float bj = biasf[j];
            #pragma unroll
            for (int r = 0; r < 4; ++r) {
                int m = row0 + wr * 64 + mi * 16 + half * 4 + r;
                float val = acc[mi][ni][r] + bj;
                if (j < 512)       qbuf[(size_t)m * 512 + j] = val;
                else if (j < 1024) kbuf[(size_t)m * 512 + (j - 512)] = f2bf(val);
                else               vbuf[(size_t)m * 512 + (j - 1024)] = f2bf(val);
            }
        }
    }
}

// ---- column-sum of v: colsum[j] = sum_m v[m][j] ----
__global__ void k_colsum(const u16* __restrict__ vbuf, float* __restrict__ colsum) {
    int t = threadIdx.x;   // 512 threads
    int b = blockIdx.x;    // 64 blocks x 64 rows
    float acc = 0.f;
    const u16* p = vbuf + (size_t)b * 64 * 512 + t;
    #pragma unroll 4
    for (int r = 0; r < 64; ++r) acc += bf2f(p[r * 512]);
    atomicAdd(&colsum[t], acc);
}

// ---- sparse attention: one block per row n ----
__global__ __launch_bounds__(256) void k_attn(const float* __restrict__ A,
        const float* __restrict__ qbuf, const u16* __restrict__ kbuf,
        const u16* __restrict__ vbuf, const float* __restrict__ colsum,
        float* __restrict__ out)
{
    const int n = blockIdx.x, tid = threadIdx.x;
    const int w = tid >> 6, lane = tid & 63;
    __shared__ float s_q[512], s_out[512];
    __shared__ int s_idx[1024];
    __shared__ int s_cnt;
    if (tid == 0) s_cnt = 0;
    s_q[tid]        = qbuf[(size_t)n * 512 + tid];
    s_q[tid + 256]  = qbuf[(size_t)n * 512 + 256 + tid];
    s_out[tid]       = 0.125f * colsum[tid];
    s_out[tid + 256] = 0.125f * colsum[tid + 256];
    __syncthreads();

    const float4* arow = (const float4*)(A + (size_t)n * NN);
    for (int c4 = tid; c4 < NN / 4; c4 += 256) {
        float4 a = arow[c4];
        int m0 = c4 * 4;
        if (a.x != 0.f) s_idx[atomicAdd(&s_cnt, 1)] = m0;
        if (a.y != 0.f) s_idx[atomicAdd(&s_cnt, 1)] = m0 + 1;
        if (a.z != 0.f) s_idx[atomicAdd(&s_cnt, 1)] = m0 + 2;
        if (a.w != 0.f) s_idx[atomicAdd(&s_cnt, 1)] = m0 + 3;
    }
    __syncthreads();
    const int cnt = s_cnt;

    float acc[8] = {0.f, 0.f, 0.f, 0.f, 0.f, 0.f, 0.f, 0.f};
    for (int i = w; i < cnt; i += 4) {
        const int m = s_idx[i];
        const u16* kr = kbuf + (size_t)m * 512;
        float s = 0.f;
        #pragma unroll
        for (int j = 0; j < 8; ++j)
            s += s_q[lane + 64 * j] * bf2f(kr[lane + 64 * j]);
        // reduce over the 8 lanes sharing lane%8 (same head)
        s += __shfl_xor(s, 8);
        s += __shfl_xor(s, 16);
        s += __shfl_xor(s, 32);
        // softmax across the 8 heads (lanes differing in bits 0..2)
        float mx = s;
        mx = fmaxf(mx, __shfl_xor(mx, 1));
        mx = fmaxf(mx, __shfl_xor(mx, 2));
        mx = fmaxf(mx, __shfl_xor(mx, 4));
        float e = __expf(s - mx);
        float Z = e;
        Z += __shfl_xor(Z, 1);
        Z += __shfl_xor(Z, 2);
        Z += __shfl_xor(Z, 4);
        const float c = e / Z - 0.125f;
        const u16* vr = vbuf + (size_t)m * 512;
        #pragma unroll
        for (int j = 0; j < 8; ++j)
            acc[j] += c * bf2f(vr[lane + 64 * j]);
    }

    // cross-wave reduction into s_out
    for (int sel = 0; sel < 4; ++sel) {
        if (w == sel) {
            #pragma unroll
            for (int j = 0; j < 8; ++j)
                s_out[lane + 64 * j] += acc[j];
        }
        __syncthreads();
    }

    // write out[h][n][d] flat = h*N*64 + n*64 + d ; s_out index = d*8+h
    for (int i2 = tid; i2 < 512; i2 += 256) {
        int hh = i2 >> 6, d = i2 & 63;
        out[(size_t)hh * (NN * 64) + (size_t)n * 64 + d] = s_out[d * 8 + hh];
    }
}

extern "C" void kernel_launch(void* const* d_in, const int* in_sizes, int n_in,
                              void* d_out, int out_size, void* d_ws, size_t ws_size,
                              hipStream_t stream)
{
    const float* A  = (const float*)d_in[0];
    const float* h  = (const float*)d_in[1];
    const float* Wq = (const float*)d_in[2];
    const float* bq = (const float*)d_in[3];
    const float* Wk = (const float*)d_in[4];
    const float* bk = (const float*)d_in[5];
    const float* Wv = (const float*)d_in[6];
    const float* bv = (const float*)d_in[7];
    float* out = (float*)d_out;

    char* ws = (char*)d_ws;
    float* qbuf   = (float*)(ws);                       // 8 MB
    u16*   kbuf   = (u16*)(ws + (8u  << 20));           // 4 MB
    u16*   vbuf   = (u16*)(ws + (12u << 20));           // 4 MB
    u16*   hb     = (u16*)(ws + (16u << 20));           // 4 MB
    u16*   wt     = (u16*)(ws + (20u << 20));           // 1.5 MB
    float* biasf  = (float*)(ws + (22u << 20));         // 6 KB
    float* colsum = (float*)(ws + (22u << 20) + 8192);  // 2 KB

    k_cvt_h<<<dim3(2048), dim3(256), 0, stream>>>((const float4*)h, hb);
    k_w<<<dim3(16, 16, 3), dim3(32, 8), 0, stream>>>(Wq, Wk, Wv, wt);
    k_bias<<<dim3(3), dim3(512), 0, stream>>>(bq, bk, bv, biasf);
    k_gemm<<<dim3(32, 12), dim3(256), 0, stream>>>(hb, wt, biasf, qbuf, kbuf, vbuf);
    hipMemsetAsync(colsum, 0, 512 * sizeof(float), stream);
    k_colsum<<<dim3(64), dim3(512), 0, stream>>>(vbuf, colsum);
    k_attn<<<dim3(4096), dim3(256), 0, stream>>>(A, qbuf, kbuf, vbuf, colsum, out);
}